// Round 7
// baseline (257.358 us; speedup 1.0000x reference)
//
#include <hip/hip_runtime.h>
#include <math.h>

#define BB 32
#define LL 2048
#define CC 1280
#define HH 160
#define LCH 32            // pool blocks per batch (each covers 64 rows)
#define LCHP 32           // partial chunks per batch
#define NBC 16            // batches per L3 chunk (16 * 10.5 MB = 168 MB < 256 MB L3)
#define NCHUNK (BB / NBC)

typedef float f4 __attribute__((ext_vector_type(4)));

// ---------------- Kernel 1: pool partials for one batch-chunk ----------------
// grid: (LCH, NBC), block 320; lane owns channels [4t, 4t+4).
// NORMAL loads: allocate x-chunk into the 256MB L3 for reuse by apply.
__global__ __launch_bounds__(320) void pool_k(
    const float* __restrict__ x, float* __restrict__ psum,
    float* __restrict__ pmax, int b0) {
  const int lcb = blockIdx.x;
  const int b   = b0 + blockIdx.y;
  const int c4  = threadIdx.x << 2;

  const float* xp = x + ((size_t)b * LL + (size_t)lcb * 64) * CC + c4;
  f4 s = {0.f, 0.f, 0.f, 0.f};
  f4 m = {-INFINITY, -INFINITY, -INFINITY, -INFINITY};

#pragma unroll 8
  for (int l = 0; l < 64; ++l) {
    f4 v = *reinterpret_cast<const f4*>(xp + (size_t)l * CC);
    s += v;
    m.x = fmaxf(m.x, v.x); m.y = fmaxf(m.y, v.y);
    m.z = fmaxf(m.z, v.z); m.w = fmaxf(m.w, v.w);
  }
  const size_t o = ((size_t)lcb * BB + b) * CC + c4;
  *reinterpret_cast<f4*>(psum + o) = s;
  *reinterpret_cast<f4*>(pmax + o) = m;
}

// ---------------- Kernel 2: finish pools + layer 1 (chunk) ----------------
// grid: 2*NBC blocks (rl<NBC: gap for b0+rl; rl>=NBC: gmp), block 320
__global__ __launch_bounds__(320) void finish_l1_k(
    const float* __restrict__ psum, const float* __restrict__ pmax,
    const float* __restrict__ w1, const float* __restrict__ b1,
    float* __restrict__ hout, int b0) {
  __shared__ float v[CC];
  __shared__ float part[HH];

  const int rl = blockIdx.x;
  const int t  = threadIdx.x;
  const bool ismax = (rl >= NBC);
  const int b = b0 + (ismax ? rl - NBC : rl);
  const int r = b + (ismax ? BB : 0);   // global hout row

  for (int c = t; c < CC; c += 320) {
    if (!ismax) {
      float s = 0.f;
      for (int lc = 0; lc < LCHP; ++lc)
        s += psum[((size_t)lc * BB + b) * CC + c];
      v[c] = s * (1.0f / (float)LL);
    } else {
      float m = -INFINITY;
      for (int lc = 0; lc < LCHP; ++lc)
        m = fmaxf(m, pmax[((size_t)lc * BB + b) * CC + c]);
      v[c] = m;
    }
  }
  __syncthreads();

  const int h  = (t < HH) ? t : t - HH;
  const int k0 = (t < HH) ? 0 : CC / 2;
  float acc = 0.f;
#pragma unroll 8
  for (int k = 0; k < CC / 2; ++k)
    acc = fmaf(v[k0 + k], w1[(size_t)(k0 + k) * HH + h], acc);
  if (t >= HH) part[h] = acc;
  __syncthreads();
  if (t < HH) {
    float a = acc + part[t] + b1[t];
    hout[(size_t)r * HH + t] = fmaxf(a, 0.f);
  }
}

// ---------------- Kernel 3: layer 2 + sigmoid -> attn (chunk) ----------------
// grid: (C/256, NBC), block 256
__global__ __launch_bounds__(256) void layer2_k(
    const float* __restrict__ hout, const float* __restrict__ w2,
    const float* __restrict__ b2, float* __restrict__ attn, int b0) {
  __shared__ float u[HH];
  const int b  = b0 + blockIdx.y;
  const int ct = blockIdx.x;
  const int t  = threadIdx.x;

  if (t < HH)
    u[t] = hout[(size_t)b * HH + t] + hout[(size_t)(b + BB) * HH + t];
  __syncthreads();

  const int c = ct * 256 + t;
  float acc = 2.0f * b2[c];
#pragma unroll 8
  for (int h = 0; h < HH; ++h)
    acc = fmaf(u[h], w2[(size_t)h * CC + c], acc);
  attn[(size_t)b * CC + c] = 1.0f / (1.0f + expf(-acc));
}

// ---------------- Kernel 4: out = x * attn (chunk; x expected L3-resident) ----------------
// grid: (NBC*L/8), block 320. NT loads: hit resident lines, mark evict-first
// (chunk is dead after this). NT stores: don't pollute L3.
__global__ __launch_bounds__(320) void apply_k(
    const float* __restrict__ x, const float* __restrict__ attn,
    float* __restrict__ out, int b0) {
  const int ri = blockIdx.x * 8;          // row index within chunk
  const int b  = b0 + (ri >> 11);         // L = 2048
  const size_t r0 = (size_t)b * LL + (ri & 2047);
  const int c4 = threadIdx.x << 2;

  const f4 a = *reinterpret_cast<const f4*>(attn + (size_t)b * CC + c4);
  const float* xp = x + r0 * CC + c4;
  float* op = out + r0 * CC + c4;

#pragma unroll
  for (int i = 0; i < 8; ++i) {
    f4 v = __builtin_nontemporal_load(reinterpret_cast<const f4*>(xp + (size_t)i * CC));
    f4 o = v * a;
    __builtin_nontemporal_store(o, reinterpret_cast<f4*>(op + (size_t)i * CC));
  }
}

extern "C" void kernel_launch(void* const* d_in, const int* in_sizes, int n_in,
                              void* d_out, int out_size, void* d_ws, size_t ws_size,
                              hipStream_t stream) {
  const float* x  = (const float*)d_in[0];
  const float* w1 = (const float*)d_in[1];
  const float* b1 = (const float*)d_in[2];
  const float* w2 = (const float*)d_in[3];
  const float* b2 = (const float*)d_in[4];
  float* out = (float*)d_out;
  float* ws  = (float*)d_ws;

  // ws layout: psum[LCHP][B][C], pmax[LCHP][B][C], hout[64][H], attn[B][C]
  float* psum = ws;
  float* pmax = psum + (size_t)LCHP * BB * CC;
  float* hout = pmax + (size_t)LCHP * BB * CC;
  float* attn = hout + (size_t)2 * BB * HH;

  for (int ch = 0; ch < NCHUNK; ++ch) {
    const int b0 = ch * NBC;
    pool_k<<<dim3(LCH, NBC), 320, 0, stream>>>(x, psum, pmax, b0);
    finish_l1_k<<<2 * NBC, 320, 0, stream>>>(psum, pmax, w1, b1, hout, b0);
    layer2_k<<<dim3(CC / 256, NBC), 256, 0, stream>>>(hout, w2, b2, attn, b0);
    apply_k<<<NBC * LL / 8, 320, 0, stream>>>(x, attn, out, b0);
  }
}